// Round 7
// baseline (9593.385 us; speedup 1.0000x reference)
//
#include <hip/hip_runtime.h>
#include <stdint.h>

#define NN 2048
#define TT 365
#define DD 16
#define HH 64
#define NBLK 256      // 8 rows per block
#define NTHR 1024     // 16 waves
#define SMEM_BYTES 117248

typedef __attribute__((ext_vector_type(4))) float f32x4;

__device__ __forceinline__ float sigmoid_(float x) { return 1.f / (1.f + __expf(-x)); }
__device__ __forceinline__ float tanh_(float x) {
  float ax = fabsf(x);
  float e = __expf(-2.f * ax);
  float r = (1.f - e) / (1.f + e);
  return x < 0.f ? -r : r;
}

// R4's fused fp32 pipeline, ONE change: output stored as fp32 (d_out is float*).
// K_t: mode 0 = phaseA only (t=0); mode 1 = phaseB(t-1)+phaseA(t); mode 2 = phaseB(364).
// State: Q fp32 [2048][64] node-major (double-buffered); G f32x4 gates; Cbuf fp32.
__global__ __launch_bounds__(NTHR) void step_kernel(
    const float* __restrict__ X, const float* __restrict__ Af,
    const float* __restrict__ Wih, const float* __restrict__ Whh,
    const float* __restrict__ Bias, const float* __restrict__ Wq,
    const float* __restrict__ Bq, const float* __restrict__ Wd,
    const float* __restrict__ Bd, float* __restrict__ Out,
    const float* __restrict__ Qr, float* __restrict__ Qw,
    const f32x4* __restrict__ Gr, f32x4* __restrict__ Gw,
    float* __restrict__ Cbuf, int tB, int mode)
{
  extern __shared__ __align__(16) char smem[];
  f32x4*  whh4   = (f32x4*)smem;                 // [64][64] f32x4   65536
  f32x4*  wih4   = (f32x4*)(smem + 65536);       // [16][64] f32x4   16384
  float2* wq2    = (float2*)(smem + 81920);      // [32][64] float2  16384
  float*  sh_red = (float*)(smem + 98304);       // [16w][16cq][16]  16384
  float*  sh_h   = (float*)(smem + 114688);      // [8][64]           2048
  float*  sh_x   = (float*)(smem + 116736);      // [8][16]            512

  const int tid = threadIdx.x;
  const int w = tid >> 6;        // wave 0..15
  const int c = tid & 63;        // lane
  const int base = blockIdx.x * 8;

  // ---- stage weights + x (only needed for phase A) ----
  if (mode != 2) {
    for (int idx = tid; idx < 64 * 64; idx += NTHR) {
      int k = idx >> 6, cc = idx & 63;
      f32x4 p = { Whh[k * 256 + cc], Whh[k * 256 + 64 + cc],
                  Whh[k * 256 + 128 + cc], Whh[k * 256 + 192 + cc] };
      whh4[idx] = p;
    }
    for (int idx = tid; idx < 16 * 64; idx += NTHR) {
      int k = idx >> 6, cc = idx & 63;
      f32x4 p = { Wih[k * 256 + cc], Wih[k * 256 + 64 + cc],
                  Wih[k * 256 + 128 + cc], Wih[k * 256 + 192 + cc] };
      wih4[idx] = p;
    }
    for (int idx = tid; idx < 32 * 64; idx += NTHR) {
      int kk = idx >> 6, cc = idx & 63;
      wq2[idx] = make_float2(Wq[(2 * kk) * 64 + cc], Wq[(2 * kk + 1) * 64 + cc]);
    }
    if (tid < 128) {
      int r = tid >> 4, k = tid & 15;
      sh_x[tid] = X[(size_t)(base + r) * (TT * DD) + (tB + 1) * DD + k];
    }
  }
  if (mode == 0 && tid < 512) sh_h[tid] = 0.f;
  __syncthreads();

  // ---- phase B: Aq = A @ q_{tB}, pure fp32 ----
  if (mode != 0) {
    const int rh  = w & 1;        // rows 4rh .. 4rh+3
    const int ksw = w >> 1;       // k base = ksw*256
    const int cq  = c & 15;       // cols 4cq .. 4cq+3
    const int ksl = c >> 4;       // k sub-slice of 64
    const int k0  = ksw * 256 + ksl * 64;
    const float4* Ar0 = (const float4*)(Af + (size_t)(base + 4 * rh) * NN + k0);
    const float4* Qp  = (const float4*)Qr + (size_t)k0 * 16 + cq;

    f32x4 acc[4];
    #pragma unroll
    for (int rr = 0; rr < 4; ++rr) acc[rr] = (f32x4){0.f, 0.f, 0.f, 0.f};

    #pragma unroll 4
    for (int i = 0; i < 16; ++i) {       // 16 quads of k -> 64 k per lane
      float4 q0 = Qp[(4 * i + 0) * 16];  // Q[k0+4i+j][4cq..4cq+3]
      float4 q1 = Qp[(4 * i + 1) * 16];
      float4 q2 = Qp[(4 * i + 2) * 16];
      float4 q3 = Qp[(4 * i + 3) * 16];
      #pragma unroll
      for (int rr = 0; rr < 4; ++rr) {
        float4 av = Ar0[rr * 512 + i];   // A[base+4rh+rr][k0+4i .. +3]
        acc[rr][0] += av.x * q0.x + av.y * q1.x + av.z * q2.x + av.w * q3.x;
        acc[rr][1] += av.x * q0.y + av.y * q1.y + av.z * q2.y + av.w * q3.y;
        acc[rr][2] += av.x * q0.z + av.y * q1.z + av.z * q2.z + av.w * q3.z;
        acc[rr][3] += av.x * q0.w + av.y * q1.w + av.z * q2.w + av.w * q3.w;
      }
    }
    // reduce over ksl (4 sub-slices) within the wave
    #pragma unroll
    for (int rr = 0; rr < 4; ++rr)
      #pragma unroll
      for (int j = 0; j < 4; ++j) {
        acc[rr][j] += __shfl_xor(acc[rr][j], 16);
        acc[rr][j] += __shfl_xor(acc[rr][j], 32);
      }
    if (c < 16) {                        // lane c holds tile (4 rows x cols 4c..4c+3)
      float* dst = sh_red + (w * 16 + c) * 16;
      #pragma unroll
      for (int rr = 0; rr < 4; ++rr)
        #pragma unroll
        for (int j = 0; j < 4; ++j) dst[rr * 4 + j] = acc[rr][j];
    }
    __syncthreads();

    if (tid < 512) {
      int r = tid >> 6, cc = tid & 63;
      int rh2 = r >> 2;
      float aqv = 0.f;
      #pragma unroll
      for (int j = 0; j < 8; ++j)        // sum the 8 k-slices (waves 2j+rh2)
        aqv += sh_red[((2 * j + rh2) * 16 + (cc >> 2)) * 16 + (r & 3) * 4 + (cc & 3)];

      size_t ci = (size_t)(base + r) * 64 + cc;
      f32x4 g = Gr[ci];                  // {i, f, g, o} from phaseA(tB)
      float cnew = g[1] * (Cbuf[ci] + aqv) + g[0] * g[2];
      float hv = g[3] * tanh_(cnew);
      Cbuf[ci] = cnew;
      sh_h[tid] = hv;

      float red = hv * Wd[cc];
      #pragma unroll
      for (int off = 32; off; off >>= 1) red += __shfl_xor(red, off);
      if (cc == 0) Out[(size_t)(base + r) * TT + tB] = red + Bd[0];  // << fp32 store
    }
    __syncthreads();
  }

  // ---- phase A: gates_{tB+1} + q_{tB+1} from h (in sh_h), fp32 ----
  if (mode != 2 && tid < 512) {
    float ai = Bias[c], af = Bias[64 + c], ag = Bias[128 + c], ao = Bias[192 + c];
    float aq = Bq[c];
    const float* shx = sh_x + w * 16;
    const float* shh = sh_h + w * 64;
    #pragma unroll
    for (int k = 0; k < 16; ++k) {
      float xv = shx[k];
      f32x4 p = wih4[k * 64 + c];
      ai += xv * p[0]; af += xv * p[1]; ag += xv * p[2]; ao += xv * p[3];
    }
    #pragma unroll 8
    for (int kk = 0; kk < 32; ++kk) {
      float h0 = shh[2 * kk], h1 = shh[2 * kk + 1];
      f32x4 p0 = whh4[(2 * kk) * 64 + c];
      f32x4 p1 = whh4[(2 * kk + 1) * 64 + c];
      float2 qw = wq2[kk * 64 + c];
      ai += h0 * p0[0] + h1 * p1[0];
      af += h0 * p0[1] + h1 * p1[1];
      ag += h0 * p0[2] + h1 * p1[2];
      ao += h0 * p0[3] + h1 * p1[3];
      aq += h0 * qw.x + h1 * qw.y;
    }
    f32x4 g = { sigmoid_(ai), sigmoid_(af), tanh_(ag), sigmoid_(ao) };
    size_t gi = (size_t)(base + w) * 64 + c;
    Gw[gi] = g;
    Qw[gi] = tanh_(aq);                  // node-major fp32, no transpose
  }
}

extern "C" void kernel_launch(void* const* d_in, const int* in_sizes, int n_in,
                              void* d_out, int out_size, void* d_ws, size_t ws_size,
                              hipStream_t stream) {
  const float* X    = (const float*)d_in[0];
  const float* Af   = (const float*)d_in[1];
  const float* Wih  = (const float*)d_in[2];
  const float* Whh  = (const float*)d_in[3];
  const float* Bias = (const float*)d_in[4];
  const float* Wq   = (const float*)d_in[5];
  const float* Bq   = (const float*)d_in[6];
  const float* Wd   = (const float*)d_in[7];
  const float* Bd   = (const float*)d_in[8];
  float* Out = (float*)d_out;            // << reference output dtype is float32

  char* ws = (char*)d_ws;
  float* Q0   = (float*)ws;                          // 512 KB
  float* Q1   = (float*)(ws + 524288);               // 512 KB
  f32x4* G0   = (f32x4*)(ws + 1048576);              // 2 MB
  f32x4* G1   = (f32x4*)(ws + 3145728);              // 2 MB
  float* Cbuf = (float*)(ws + 5242880);              // 512 KB

  hipFuncSetAttribute((const void*)step_kernel,
                      hipFuncAttributeMaxDynamicSharedMemorySize, SMEM_BYTES);
  hipMemsetAsync(Cbuf, 0, (size_t)NN * HH * 4, stream);

  for (int t = 0; t <= TT; ++t) {
    int mode = (t == 0) ? 0 : (t == TT) ? 2 : 1;
    const float* qr = (t & 1) ? Q0 : Q1;    // phaseB reads q[(t-1)&1]
    float* qw       = (t & 1) ? Q1 : Q0;    // phaseA writes q[t&1]
    const f32x4* gr = (t & 1) ? G0 : G1;
    f32x4* gw       = (t & 1) ? G1 : G0;
    hipLaunchKernelGGL(step_kernel, dim3(NBLK), dim3(NTHR), SMEM_BYTES, stream,
                       X, Af, Wih, Whh, Bias, Wq, Bq, Wd, Bd, Out,
                       qr, qw, gr, gw, Cbuf, t - 1, mode);
  }
}